// Round 17
// baseline (98.358 us; speedup 1.0000x reference)
//
#include <hip/hip_runtime.h>
#include <hip/hip_bf16.h>
#include <stdint.h>

#define N_NODES 4096
#define INF_ 512
#define OUTF_ 512

typedef unsigned short u16;
typedef __attribute__((ext_vector_type(8))) short bf16x8;
typedef __attribute__((ext_vector_type(4))) float f32x4;

__device__ __forceinline__ u16 f2bf(float f) {
    union { float f; uint32_t u; } v; v.f = f;
    uint32_t u = v.u;
    uint32_t r = u + 0x7FFFu + ((u >> 16) & 1u);   // round-to-nearest-even
    return (u16)(r >> 16);
}
__device__ __forceinline__ float bf2f(u16 h) {
    union { uint32_t u; float f; } v; v.u = ((uint32_t)h) << 16;
    return v.f;
}

__device__ __forceinline__ void async16(const void* gsrc, void* ldst) {
    __builtin_amdgcn_global_load_lds(
        (const __attribute__((address_space(1))) unsigned int*)gsrc,
        (__attribute__((address_space(3))) unsigned int*)ldst,
        16, 0, 0);
}

// ---- convert W -> bf16 transposed [OUTF][INF] only (X handled in support) ----
__global__ void convertW_kernel(const float* __restrict__ W, u16* __restrict__ WT) {
    int tid = blockIdx.x * blockDim.x + threadIdx.x;   // 256K threads
    int n = tid >> 9, k = tid & 511;
    WT[tid] = f2bf(W[k * OUTF_ + n]);   // WT[n][k] = W[k][n]
}

// ---- support body: ST = (X@W)^T bf16, 64x128 tile; A reg-staged from fp32 X ----
// (hidden under prep; internal latency exposure tolerated) (R16-verified)
__device__ __forceinline__ void support_body(u16 (*As)[40], u16 (*Bs)[32],
                                             const float* __restrict__ X, const u16* __restrict__ B,
                                             u16* __restrict__ outT, int sx, int sy) {
    const int K = 512;
    const int tid  = threadIdx.x;
    const int lane = tid & 63;
    const int w    = tid >> 6;
    const int wr   = w >> 1;
    const int wc   = w & 1;
    const int brow = sx * 64;
    const int bcol = sy * 128;

    f32x4 acc[2][4] = {};
    const int ar = tid >> 2;
    const int aq = (tid & 3) * 8;
    const int srB = w * 32 + (lane >> 2);
    const int sc  = (lane & 3) * 8;

    for (int kt = 0; kt < K; kt += 32) {
        __syncthreads();
        async16(&B[(long)(bcol + srB) * K + kt + sc],      &Bs[w * 32][0]);
        async16(&B[(long)(bcol + srB + 16) * K + kt + sc], &Bs[w * 32 + 16][0]);
        {
            const float* xs = X + (long)(brow + ar) * K + kt + aq;
            float4 x0 = *(const float4*)xs;
            float4 x1 = *(const float4*)(xs + 4);
            union { bf16x8 v; u16 h[8]; } pk;
            pk.h[0] = f2bf(x0.x); pk.h[1] = f2bf(x0.y); pk.h[2] = f2bf(x0.z); pk.h[3] = f2bf(x0.w);
            pk.h[4] = f2bf(x1.x); pk.h[5] = f2bf(x1.y); pk.h[6] = f2bf(x1.z); pk.h[7] = f2bf(x1.w);
            *(bf16x8*)&As[ar][aq] = pk.v;
        }
        __syncthreads();

        bf16x8 af[2], bfr[4];
#pragma unroll
        for (int m = 0; m < 2; ++m)
            af[m] = *(const bf16x8*)&As[wr * 32 + m * 16 + (lane & 15)][(lane >> 4) * 8];
#pragma unroll
        for (int n = 0; n < 4; ++n)
            bfr[n] = *(const bf16x8*)&Bs[wc * 64 + n * 16 + (lane & 15)][(lane >> 4) * 8];
#pragma unroll
        for (int m = 0; m < 2; ++m)
#pragma unroll
            for (int n = 0; n < 4; ++n)
                acc[m][n] = __builtin_amdgcn_mfma_f32_16x16x32_bf16(af[m], bfr[n], acc[m][n], 0, 0, 0);
    }

#pragma unroll
    for (int m = 0; m < 2; ++m)
#pragma unroll
        for (int n = 0; n < 4; ++n) {
            int col  = bcol + wc * 64 + n * 16 + (lane & 15);
            int row0 = brow + wr * 32 + m * 16 + (lane >> 4) * 4;
#pragma unroll
            for (int r = 0; r < 4; ++r)
                outT[(long)col * N_NODES + row0 + r] = f2bf(acc[m][n][r]);
        }
}

// ---- mixed: blocks 0-255 = support GEMM (from fp32 X); 256-8447 = E->Abf prep ----
__global__ __launch_bounds__(256)
void mixed_ps(const float* __restrict__ X, const u16* __restrict__ WT, u16* __restrict__ ST,
              const float4* __restrict__ E4, const float* __restrict__ wq,
              u16* __restrict__ Abf) {
    __shared__ u16 As[64][40];
    __shared__ u16 Bs[128][32];
    const int g = blockIdx.x;
    if (g < 256) {
        support_body(As, Bs, X, WT, ST, g & 63, g >> 6);
    } else {
        const float w0 = wq[0], w1 = wq[1], w2 = wq[2], w3 = wq[3];
        const long f = ((long)(g - 256) * 256 + threadIdx.x) * 8;   // float4-flat 0..16.7M
        float4 ev[8];
#pragma unroll
        for (int j = 0; j < 8; ++j) ev[j] = E4[f + j];
        union { bf16x8 v; u16 h[8]; } pk;
#pragma unroll
        for (int j = 0; j < 8; ++j)
            pk.h[j] = f2bf(ev[j].x * w0 + ev[j].y * w1 + ev[j].z * w2 + ev[j].w * w3);
        *(bf16x8*)(Abf + f) = pk.v;
    }
}

// ---- gemm2: parts[z] = bf16(Abf[:,zc] @ S[zc,:]). 64x64 tile, BK=64 swizzled,
// split-K x4, grid (64,8,4)=2048 blocks = 8/CU (32 waves/CU, HW max). LDS 16KB.
// __launch_bounds__(256,8) caps VGPR at 64. Wave-tile 32x32 (2x2 waves). ----
__global__ __launch_bounds__(256, 8)
void gemm2_64(const u16* __restrict__ A, const u16* __restrict__ B,
              u16* __restrict__ parts) {
    const int K = 4096;
    __shared__ u16 As[64][64];
    __shared__ u16 Bs[64][64];

    const int tid  = threadIdx.x;
    const int lane = tid & 63;
    const int w    = tid >> 6;        // wave 0..3
    const int wr   = w >> 1;          // 0..1 (32-row halves)
    const int wc   = w & 1;           // 0..1 (32-col halves)
    const int brow = blockIdx.x * 64;
    const int bcol = blockIdx.y * 64;
    const int kt0  = blockIdx.z * 1024;

    f32x4 acc[2][2] = {};

    const int srow = lane >> 3;                 // row within 8-row staging group
    const int sk   = ((lane & 7) ^ srow) * 8;   // pre-swizzled source k-offset (u16)

    for (int kt = kt0; kt < kt0 + 1024; kt += 64) {
        __syncthreads();
#pragma unroll
        for (int j = 0; j < 2; ++j) {
            async16(&A[(long)(brow + w * 16 + j * 8 + srow) * K + kt + sk], &As[w * 16 + j * 8][0]);
            async16(&B[(long)(bcol + w * 16 + j * 8 + srow) * K + kt + sk], &Bs[w * 16 + j * 8][0]);
        }
        __syncthreads();   // vmcnt(0) drain -> tiles valid

#pragma unroll
        for (int h = 0; h < 2; ++h) {
            const int po = ((h * 4 + (lane >> 4)) ^ (lane & 7)) * 8;   // phys u16 offset
            bf16x8 af[2], bfr[2];
#pragma unroll
            for (int m = 0; m < 2; ++m)
                af[m] = *(const bf16x8*)&As[wr * 32 + m * 16 + (lane & 15)][po];
#pragma unroll
            for (int n = 0; n < 2; ++n)
                bfr[n] = *(const bf16x8*)&Bs[wc * 32 + n * 16 + (lane & 15)][po];
#pragma unroll
            for (int m = 0; m < 2; ++m)
#pragma unroll
                for (int n = 0; n < 2; ++n)
                    acc[m][n] = __builtin_amdgcn_mfma_f32_16x16x32_bf16(af[m], bfr[n], acc[m][n], 0, 0, 0);
        }
    }

    // epilogue -> bf16 partials. C/D: col=lane&15, row=(lane>>4)*4+reg (verified R1-R16)
    u16* outP = parts + (long)blockIdx.z * (N_NODES * OUTF_);
#pragma unroll
    for (int m = 0; m < 2; ++m)
#pragma unroll
        for (int n = 0; n < 2; ++n) {
            int col  = bcol + wc * 32 + n * 16 + (lane & 15);
            int row0 = brow + wr * 32 + m * 16 + (lane >> 4) * 4;
#pragma unroll
            for (int r = 0; r < 4; ++r)
                outP[(long)(row0 + r) * OUTF_ + col] = f2bf(acc[m][n][r]);
        }
}

// ---- reduce 4 bf16 split-K partials + bias -> fp32 out (R15/R16-verified) ----
__global__ void reduce4_kernel(const u16* __restrict__ parts, const float* __restrict__ bias,
                               float* __restrict__ out) {
    const int t = blockIdx.x * blockDim.x + threadIdx.x;   // 256K threads, 8 elems each
    const long base = (long)t * 8;
    const int col0 = (int)(base & (OUTF_ - 1));
    const long stride = (long)N_NODES * OUTF_;

    float s[8];
#pragma unroll
    for (int j = 0; j < 8; ++j) s[j] = bias[col0 + j];
#pragma unroll
    for (int z = 0; z < 4; ++z) {
        bf16x8 v = *(const bf16x8*)(parts + z * stride + base);
#pragma unroll
        for (int j = 0; j < 8; ++j) s[j] += bf2f((u16)v[j]);
    }
    float4* o4 = (float4*)(out + base);
    o4[0] = make_float4(s[0], s[1], s[2], s[3]);
    o4[1] = make_float4(s[4], s[5], s[6], s[7]);
}

extern "C" void kernel_launch(void* const* d_in, const int* in_sizes, int n_in,
                              void* d_out, int out_size, void* d_ws, size_t ws_size,
                              hipStream_t stream) {
    const float* X    = (const float*)d_in[0];
    // d_in[1] = adj, unused by forward
    const float* E    = (const float*)d_in[2];
    const float* W    = (const float*)d_in[3];
    const float* wq   = (const float*)d_in[4];
    const float* bias = (const float*)d_in[5];
    float* out = (float*)d_out;

    char* ws = (char*)d_ws;
    u16* ST    = (u16*)ws;                     // 512 x 4096 bf16 (support^T), 4 MB
    u16* WT    = (u16*)(ws + (4l << 20));      // 512 x 512 bf16, 0.5 MB
    u16* Abf   = (u16*)(ws + (9l << 20));      // 4096 x 4096 bf16, 32 MB
    u16* parts = (u16*)(ws + (41l << 20));     // 4 x 4096 x 512 bf16, 16 MB

    // 1) W -> WT bf16 (~1us)
    convertW_kernel<<<1024, 256, 0, stream>>>(W, WT);
    // 2) support GEMM (reg-staged fp32 X) hidden under full E->Abf prep (~48us)
    mixed_ps<<<8448, 256, 0, stream>>>(X, WT, ST, (const float4*)E, wq, Abf);
    // 3) parts[z] = Abf[:,zc] @ S[zc,:] — 64x64 tile, BK=64, 8 blocks/CU
    gemm2_64<<<dim3(64, 8, 4), 256, 0, stream>>>(Abf, ST, parts);
    // 4) out = sum_z parts[z] + bias (~4us)
    reduce4_kernel<<<1024, 256, 0, stream>>>(parts, bias, out);
}

// Round 18
// 94.088 us; speedup vs baseline: 1.0454x; 1.0454x over previous
//
#include <hip/hip_runtime.h>
#include <hip/hip_bf16.h>
#include <stdint.h>

#define N_NODES 4096
#define INF_ 512
#define OUTF_ 512

typedef unsigned short u16;
typedef __attribute__((ext_vector_type(8))) short bf16x8;
typedef __attribute__((ext_vector_type(4))) float f32x4;

__device__ __forceinline__ u16 f2bf(float f) {
    union { float f; uint32_t u; } v; v.f = f;
    uint32_t u = v.u;
    uint32_t r = u + 0x7FFFu + ((u >> 16) & 1u);   // round-to-nearest-even
    return (u16)(r >> 16);
}
__device__ __forceinline__ float bf2f(u16 h) {
    union { uint32_t u; float f; } v; v.u = ((uint32_t)h) << 16;
    return v.f;
}

__device__ __forceinline__ void async16(const void* gsrc, void* ldst) {
    __builtin_amdgcn_global_load_lds(
        (const __attribute__((address_space(1))) unsigned int*)gsrc,
        (__attribute__((address_space(3))) unsigned int*)ldst,
        16, 0, 0);
}

// ---- convert W -> bf16 transposed [OUTF][INF] only (X handled in support) ----
__global__ void convertW_kernel(const float* __restrict__ W, u16* __restrict__ WT) {
    int tid = blockIdx.x * blockDim.x + threadIdx.x;   // 256K threads
    int n = tid >> 9, k = tid & 511;
    WT[tid] = f2bf(W[k * OUTF_ + n]);   // WT[n][k] = W[k][n]
}

// ---- support body: ST = (X@W)^T bf16, 64x128 tile; A reg-staged from fp32 X ----
// (hidden under prep; internal latency exposure tolerated) (R16-verified)
__device__ __forceinline__ void support_body(u16 (*As)[40], u16 (*Bs)[32],
                                             const float* __restrict__ X, const u16* __restrict__ B,
                                             u16* __restrict__ outT, int sx, int sy) {
    const int K = 512;
    const int tid  = threadIdx.x;
    const int lane = tid & 63;
    const int w    = tid >> 6;
    const int wr   = w >> 1;
    const int wc   = w & 1;
    const int brow = sx * 64;
    const int bcol = sy * 128;

    f32x4 acc[2][4] = {};
    const int ar = tid >> 2;
    const int aq = (tid & 3) * 8;
    const int srB = w * 32 + (lane >> 2);
    const int sc  = (lane & 3) * 8;

    for (int kt = 0; kt < K; kt += 32) {
        __syncthreads();
        async16(&B[(long)(bcol + srB) * K + kt + sc],      &Bs[w * 32][0]);
        async16(&B[(long)(bcol + srB + 16) * K + kt + sc], &Bs[w * 32 + 16][0]);
        {
            const float* xs = X + (long)(brow + ar) * K + kt + aq;
            float4 x0 = *(const float4*)xs;
            float4 x1 = *(const float4*)(xs + 4);
            union { bf16x8 v; u16 h[8]; } pk;
            pk.h[0] = f2bf(x0.x); pk.h[1] = f2bf(x0.y); pk.h[2] = f2bf(x0.z); pk.h[3] = f2bf(x0.w);
            pk.h[4] = f2bf(x1.x); pk.h[5] = f2bf(x1.y); pk.h[6] = f2bf(x1.z); pk.h[7] = f2bf(x1.w);
            *(bf16x8*)&As[ar][aq] = pk.v;
        }
        __syncthreads();

        bf16x8 af[2], bfr[4];
#pragma unroll
        for (int m = 0; m < 2; ++m)
            af[m] = *(const bf16x8*)&As[wr * 32 + m * 16 + (lane & 15)][(lane >> 4) * 8];
#pragma unroll
        for (int n = 0; n < 4; ++n)
            bfr[n] = *(const bf16x8*)&Bs[wc * 64 + n * 16 + (lane & 15)][(lane >> 4) * 8];
#pragma unroll
        for (int m = 0; m < 2; ++m)
#pragma unroll
            for (int n = 0; n < 4; ++n)
                acc[m][n] = __builtin_amdgcn_mfma_f32_16x16x32_bf16(af[m], bfr[n], acc[m][n], 0, 0, 0);
    }

#pragma unroll
    for (int m = 0; m < 2; ++m)
#pragma unroll
        for (int n = 0; n < 4; ++n) {
            int col  = bcol + wc * 64 + n * 16 + (lane & 15);
            int row0 = brow + wr * 32 + m * 16 + (lane >> 4) * 4;
#pragma unroll
            for (int r = 0; r < 4; ++r)
                outT[(long)col * N_NODES + row0 + r] = f2bf(acc[m][n][r]);
        }
}

// ---- mixed: blocks 0-255 = support GEMM (from fp32 X); 256-8447 = E->Abf prep ----
__global__ __launch_bounds__(256)
void mixed_ps(const float* __restrict__ X, const u16* __restrict__ WT, u16* __restrict__ ST,
              const float4* __restrict__ E4, const float* __restrict__ wq,
              u16* __restrict__ Abf) {
    __shared__ u16 As[64][40];
    __shared__ u16 Bs[128][32];
    const int g = blockIdx.x;
    if (g < 256) {
        support_body(As, Bs, X, WT, ST, g & 63, g >> 6);
    } else {
        const float w0 = wq[0], w1 = wq[1], w2 = wq[2], w3 = wq[3];
        const long f = ((long)(g - 256) * 256 + threadIdx.x) * 8;   // float4-flat 0..16.7M
        float4 ev[8];
#pragma unroll
        for (int j = 0; j < 8; ++j) ev[j] = E4[f + j];
        union { bf16x8 v; u16 h[8]; } pk;
#pragma unroll
        for (int j = 0; j < 8; ++j)
            pk.h[j] = f2bf(ev[j].x * w0 + ev[j].y * w1 + ev[j].z * w2 + ev[j].w * w3);
        *(bf16x8*)(Abf + f) = pk.v;
    }
}

// ---- gemm2: parts[z] = bf16(Abf[:,zc] @ S[zc,:]). 64x128 tile, BK=64 swizzled
// (R14/R15-verified octet swizzle), split-K x4, grid (64,4,4)=1024 blocks,
// LDS 24KB -> 6 blocks/CU TLP. K-chunk 1024 = 16 iters. (R15/R16-verbatim;
// tile ladder: 128x128@4/CU=43, 64x128@6/CU=38 [optimum], 64x64@8/CU=42) ----
__global__ __launch_bounds__(256)
void gemm2_k64(const u16* __restrict__ A, const u16* __restrict__ B,
               u16* __restrict__ parts) {
    const int K = 4096;
    __shared__ u16 As[64][64];
    __shared__ u16 Bs[128][64];

    const int tid  = threadIdx.x;
    const int lane = tid & 63;
    const int w    = tid >> 6;        // wave 0..3
    const int wr   = w >> 1;          // 0..1 (32-row halves)
    const int wc   = w & 1;           // 0..1 (64-col halves)
    const int brow = blockIdx.x * 64;
    const int bcol = blockIdx.y * 128;
    const int kt0  = blockIdx.z * 1024;

    f32x4 acc[2][4] = {};

    const int srow = lane >> 3;                 // row within 8-row staging group
    const int sk   = ((lane & 7) ^ srow) * 8;   // pre-swizzled source k-offset (u16)

    for (int kt = kt0; kt < kt0 + 1024; kt += 64) {
        __syncthreads();
#pragma unroll
        for (int j = 0; j < 2; ++j)
            async16(&A[(long)(brow + w * 16 + j * 8 + srow) * K + kt + sk], &As[w * 16 + j * 8][0]);
#pragma unroll
        for (int j = 0; j < 4; ++j)
            async16(&B[(long)(bcol + w * 32 + j * 8 + srow) * K + kt + sk], &Bs[w * 32 + j * 8][0]);
        __syncthreads();   // vmcnt(0) drain -> tiles valid

#pragma unroll
        for (int h = 0; h < 2; ++h) {
            const int po = ((h * 4 + (lane >> 4)) ^ (lane & 7)) * 8;   // phys u16 offset
            bf16x8 af[2], bfr[4];
#pragma unroll
            for (int m = 0; m < 2; ++m)
                af[m] = *(const bf16x8*)&As[wr * 32 + m * 16 + (lane & 15)][po];
#pragma unroll
            for (int n = 0; n < 4; ++n)
                bfr[n] = *(const bf16x8*)&Bs[wc * 64 + n * 16 + (lane & 15)][po];
#pragma unroll
            for (int m = 0; m < 2; ++m)
#pragma unroll
                for (int n = 0; n < 4; ++n)
                    acc[m][n] = __builtin_amdgcn_mfma_f32_16x16x32_bf16(af[m], bfr[n], acc[m][n], 0, 0, 0);
        }
    }

    // epilogue -> bf16 partials. C/D: col=lane&15, row=(lane>>4)*4+reg (verified R1-R17)
    u16* outP = parts + (long)blockIdx.z * (N_NODES * OUTF_);
#pragma unroll
    for (int m = 0; m < 2; ++m)
#pragma unroll
        for (int n = 0; n < 4; ++n) {
            int col  = bcol + wc * 64 + n * 16 + (lane & 15);
            int row0 = brow + wr * 32 + m * 16 + (lane >> 4) * 4;
#pragma unroll
            for (int r = 0; r < 4; ++r)
                outP[(long)(row0 + r) * OUTF_ + col] = f2bf(acc[m][n][r]);
        }
}

// ---- reduce 4 bf16 split-K partials + bias -> fp32 out (R15/R16-verified) ----
__global__ void reduce4_kernel(const u16* __restrict__ parts, const float* __restrict__ bias,
                               float* __restrict__ out) {
    const int t = blockIdx.x * blockDim.x + threadIdx.x;   // 256K threads, 8 elems each
    const long base = (long)t * 8;
    const int col0 = (int)(base & (OUTF_ - 1));
    const long stride = (long)N_NODES * OUTF_;

    float s[8];
#pragma unroll
    for (int j = 0; j < 8; ++j) s[j] = bias[col0 + j];
#pragma unroll
    for (int z = 0; z < 4; ++z) {
        bf16x8 v = *(const bf16x8*)(parts + z * stride + base);
#pragma unroll
        for (int j = 0; j < 8; ++j) s[j] += bf2f((u16)v[j]);
    }
    float4* o4 = (float4*)(out + base);
    o4[0] = make_float4(s[0], s[1], s[2], s[3]);
    o4[1] = make_float4(s[4], s[5], s[6], s[7]);
}

extern "C" void kernel_launch(void* const* d_in, const int* in_sizes, int n_in,
                              void* d_out, int out_size, void* d_ws, size_t ws_size,
                              hipStream_t stream) {
    const float* X    = (const float*)d_in[0];
    // d_in[1] = adj, unused by forward
    const float* E    = (const float*)d_in[2];
    const float* W    = (const float*)d_in[3];
    const float* wq   = (const float*)d_in[4];
    const float* bias = (const float*)d_in[5];
    float* out = (float*)d_out;

    char* ws = (char*)d_ws;
    u16* ST    = (u16*)ws;                     // 512 x 4096 bf16 (support^T), 4 MB
    u16* WT    = (u16*)(ws + (4l << 20));      // 512 x 512 bf16, 0.5 MB
    u16* Abf   = (u16*)(ws + (9l << 20));      // 4096 x 4096 bf16, 32 MB
    u16* parts = (u16*)(ws + (41l << 20));     // 4 x 4096 x 512 bf16, 16 MB

    // 1) W -> WT bf16 (~1us)
    convertW_kernel<<<1024, 256, 0, stream>>>(W, WT);
    // 2) support GEMM (reg-staged fp32 X) hidden under full E->Abf prep (~48us, BW floor)
    mixed_ps<<<8448, 256, 0, stream>>>(X, WT, ST, (const float4*)E, wq, Abf);
    // 3) parts[z] = Abf[:,zc] @ S[zc,:] — 64x128 tile, BK=64, 6 blocks/CU
    gemm2_k64<<<dim3(64, 4, 4), 256, 0, stream>>>(Abf, ST, parts);
    // 4) out = sum_z parts[z] + bias (~4us)
    reduce4_kernel<<<1024, 256, 0, stream>>>(parts, bias, out);
}